// Round 1
// 971.780 us; speedup vs baseline: 1.0951x; 1.0951x over previous
//
#include <hip/hip_runtime.h>

// GCN: out = prelu(GCNConv2(prelu(GCNConv1(x)))), proj = MLP(out)
// R4b: hierarchical scan + split-bf16 MFMA GEMMs
//     (A = A_hi + A_lo truncated bf16; D = Ah*Bh + Ah*Bl + Al*Bh, err ~2^-16).
//     GEMM reads A-fragments straight from global (per-lane 32B), B-fragments
//     from pre-transposed [n][k] bf16 weights -> no LDS, no barriers.
// R5: agg128 edge loop unrolled 8-wide with predicated tail (8 gathers in
//     flight per wave; was latency-bound at ~1 gather in flight, 67 cyc/iter/CU).

typedef __attribute__((ext_vector_type(4))) float  f32x4;
typedef __attribute__((ext_vector_type(8))) __bf16 bf16x8;
typedef __attribute__((ext_vector_type(8))) short  short8;

__device__ __forceinline__ bf16x8 as_bf(short8 s) {
    union { short8 s; bf16x8 b; } u; u.s = s; return u.b;
}

// truncation split: x = hi + lo + eps, |eps| <= 2^-16 |x|
__device__ __forceinline__ short2 split1(float x) {
    unsigned u = __float_as_uint(x);
    short hi = (short)(u >> 16);
    float hif = __uint_as_float(u & 0xFFFF0000u);
    short lo = (short)(__float_as_uint(x - hif) >> 16);
    return make_short2(hi, lo);
}

// ---------------- degree count ----------------
__global__ void deg_kernel(const int* __restrict__ dst, int* __restrict__ deg, int E) {
    int e = blockIdx.x * blockDim.x + threadIdx.x;
    if (e < E) atomicAdd(&deg[dst[e]], 1);
}

// ---------------- scan phase 1: per-block (1024 elems) sum + dinv ----------------
__global__ __launch_bounds__(256)
void part_kernel(const int* __restrict__ deg, int* __restrict__ bsum,
                 float* __restrict__ dinv, int n) {
    int tid = threadIdx.x;
    int base = blockIdx.x * 1024 + tid * 4;
    int d[4] = {0, 0, 0, 0};
    if (base + 3 < n) {
        int4 v = *(const int4*)(deg + base);
        d[0] = v.x; d[1] = v.y; d[2] = v.z; d[3] = v.w;
    } else {
        for (int j = 0; j < 4; ++j) if (base + j < n) d[j] = deg[base + j];
    }
    for (int j = 0; j < 4; ++j)
        if (base + j < n) dinv[base + j] = rsqrtf((float)(d[j] + 1));
    int s = d[0] + d[1] + d[2] + d[3];
    for (int off = 32; off > 0; off >>= 1) s += __shfl_down(s, off);
    __shared__ int wsum[4];
    if ((tid & 63) == 0) wsum[tid >> 6] = s;
    __syncthreads();
    if (tid == 0) bsum[blockIdx.x] = wsum[0] + wsum[1] + wsum[2] + wsum[3];
}

// ---------------- scan phase 2: single block over block sums ----------------
__global__ __launch_bounds__(1024)
void topscan_kernel(const int* __restrict__ bsum, int* __restrict__ bbase, int nb) {
    __shared__ int sh[1024];
    int tid = threadIdx.x;
    int own = (tid < nb) ? bsum[tid] : 0;
    sh[tid] = own;
    __syncthreads();
    for (int off = 1; off < 1024; off <<= 1) {
        int t = (tid >= off) ? sh[tid - off] : 0;
        __syncthreads();
        sh[tid] += t;
        __syncthreads();
    }
    if (tid < nb) bbase[tid] = sh[tid] - own;   // exclusive
}

// ---------------- scan phase 3: per-block local scan + base -> offsets ----------------
__global__ __launch_bounds__(256)
void offs_kernel(const int* __restrict__ deg, const int* __restrict__ bbase,
                 int* __restrict__ offsets, int n) {
    int tid = threadIdx.x;
    int base = blockIdx.x * 1024 + tid * 4;
    int d[4] = {0, 0, 0, 0};
    if (base + 3 < n) {
        int4 v = *(const int4*)(deg + base);
        d[0] = v.x; d[1] = v.y; d[2] = v.z; d[3] = v.w;
    } else {
        for (int j = 0; j < 4; ++j) if (base + j < n) d[j] = deg[base + j];
    }
    int s = d[0] + d[1] + d[2] + d[3];
    __shared__ int sh[256];
    sh[tid] = s;
    __syncthreads();
    for (int off = 1; off < 256; off <<= 1) {
        int t = (tid >= off) ? sh[tid - off] : 0;
        __syncthreads();
        sh[tid] += t;
        __syncthreads();
    }
    int run = bbase[blockIdx.x] + sh[tid] - s;   // exclusive prefix for this thread
    for (int j = 0; j < 4; ++j) {
        int idx = base + j;
        if (idx <= n) offsets[idx] = run;        // also writes offsets[n]
        if (idx < n) run += d[j];
    }
}

// ---------------- CSR fill ----------------
__global__ void fill_kernel(const int* __restrict__ src, const int* __restrict__ dst,
                            const int* __restrict__ offsets, int* __restrict__ cursor,
                            int* __restrict__ csr, int E) {
    int e = blockIdx.x * blockDim.x + threadIdx.x;
    if (e < E) {
        int d = dst[e];
        int pos = offsets[d] + atomicAdd(&cursor[d], 1);
        csr[pos] = src[e];
    }
}

// ---------------- weight convert: W[K][N] fp32 -> Wt_hi/lo[n][k] bf16 ----------------
__global__ void wconv_kernel(const float* __restrict__ W, short* __restrict__ Wt_hi,
                             short* __restrict__ Wt_lo, int K, int N) {
    int idx = blockIdx.x * blockDim.x + threadIdx.x;
    if (idx >= K * N) return;
    int nn = idx / K, kk = idx - nn * K;
    short2 s = split1(W[(size_t)kk * N + nn]);
    Wt_hi[idx] = s.x;
    Wt_lo[idx] = s.y;
}

// ---------------- aggregation over dim-128 rows, 1 wave per node ----------------
// out[v] = epi( dinv[v] * ( dinv[v]*g[v] + sum_{s->v} dinv[s]*g[s] ) )
// Edge loop is 8-wide: 8 independent 512B row-gathers in flight per wave.
// Tail is predicated (index clamped to end-1, weight forced to 0 -> exact).
__global__ __launch_bounds__(256)
void agg128_kernel(const float* __restrict__ g, const int* __restrict__ csr,
                   const int* __restrict__ offsets, const float* __restrict__ dinv,
                   const float* __restrict__ bias, const float* __restrict__ a_ptr,
                   float* __restrict__ out, int n) {
    int w = threadIdx.x >> 6;
    int lane = threadIdx.x & 63;
    int v = blockIdx.x * 4 + w;
    if (v >= n) return;
    const char* gb = (const char*)g;          // 32-bit voffset form (51.2 MB buffer)
    unsigned loff = (unsigned)lane * 8u;
    float dv = dinv[v];
    float2 self = *(const float2*)(gb + ((unsigned)v * 512u + loff));
    float accx = dv * self.x;
    float accy = dv * self.y;
    int e = offsets[v], end = offsets[v + 1];
#pragma unroll 1
    for (; e < end; e += 8) {
        int   idx[8];
        float dd[8];
        float2 mm[8];
#pragma unroll
        for (int j = 0; j < 8; ++j) {
            int ee = e + j;
            idx[j] = csr[ee < end ? ee : end - 1];   // clamped dup -> cache hit
        }
#pragma unroll
        for (int j = 0; j < 8; ++j)
            dd[j] = (e + j < end) ? dinv[idx[j]] : 0.f;
#pragma unroll
        for (int j = 0; j < 8; ++j)
            mm[j] = *(const float2*)(gb + ((unsigned)idx[j] * 512u + loff));
#pragma unroll
        for (int j = 0; j < 8; ++j) {
            accx += dd[j] * mm[j].x;
            accy += dd[j] * mm[j].y;
        }
    }
    accx *= dv;
    accy *= dv;
    if (bias) {
        float a = *a_ptr;
        float2 bb = ((const float2*)bias)[lane];
        accx += bb.x;
        accy += bb.y;
        accx = accx >= 0.f ? accx : a * accx;
        accy = accy >= 0.f ? accy : a * accy;
    }
    float2 r; r.x = accx; r.y = accy;
    ((float2*)out)[(size_t)v * 64 + lane] = r;
}

// ---------------- split-bf16 MFMA GEMM: C = epi(A[MxK] @ B[KxN] + bias) ----------------
// Bt_hi/Bt_lo are [N][K] bf16 (fragment-order). 256 thr = 4 waves, block tile 64x64,
// wave tile 16x64 (4 MFMA n-tiles). No LDS. act: 0=none, 1=relu, 2=prelu(a).
__global__ __launch_bounds__(256)
void gemm_kernel(const float* __restrict__ A, const short* __restrict__ Bt_hi,
                 const short* __restrict__ Bt_lo, float* __restrict__ C,
                 int M, int K, int N,
                 const float* __restrict__ bias, int act,
                 const float* __restrict__ a_ptr) {
    const int tid = threadIdx.x;
    const int wave = tid >> 6, lane = tid & 63;
    const int quad = lane >> 4, l16 = lane & 15;
    const int row0 = blockIdx.x * 64 + wave * 16;
    const int col0 = blockIdx.y * 64;
    const int m = row0 + l16;
    const int mc = m < M ? m : M - 1;
    const float* Arow = A + (size_t)mc * K + quad * 8;

    f32x4 acc[4] = {{0.f, 0.f, 0.f, 0.f}, {0.f, 0.f, 0.f, 0.f},
                    {0.f, 0.f, 0.f, 0.f}, {0.f, 0.f, 0.f, 0.f}};

    for (int k0 = 0; k0 < K; k0 += 32) {
        float4 av0 = *(const float4*)(Arow + k0);
        float4 av1 = *(const float4*)(Arow + k0 + 4);
        short8 ah, al;
        short2 s;
        s = split1(av0.x); ah[0] = s.x; al[0] = s.y;
        s = split1(av0.y); ah[1] = s.x; al[1] = s.y;
        s = split1(av0.z); ah[2] = s.x; al[2] = s.y;
        s = split1(av0.w); ah[3] = s.x; al[3] = s.y;
        s = split1(av1.x); ah[4] = s.x; al[4] = s.y;
        s = split1(av1.y); ah[5] = s.x; al[5] = s.y;
        s = split1(av1.z); ah[6] = s.x; al[6] = s.y;
        s = split1(av1.w); ah[7] = s.x; al[7] = s.y;
        bf16x8 a_hi = as_bf(ah), a_lo = as_bf(al);
#pragma unroll
        for (int t = 0; t < 4; ++t) {
            size_t boff = (size_t)(col0 + t * 16 + l16) * K + k0 + quad * 8;
            bf16x8 b_hi = as_bf(*(const short8*)(Bt_hi + boff));
            bf16x8 b_lo = as_bf(*(const short8*)(Bt_lo + boff));
            acc[t] = __builtin_amdgcn_mfma_f32_16x16x32_bf16(a_hi, b_hi, acc[t], 0, 0, 0);
            acc[t] = __builtin_amdgcn_mfma_f32_16x16x32_bf16(a_hi, b_lo, acc[t], 0, 0, 0);
            acc[t] = __builtin_amdgcn_mfma_f32_16x16x32_bf16(a_lo, b_hi, acc[t], 0, 0, 0);
        }
    }

    float a = (act == 2) ? *a_ptr : 0.f;
#pragma unroll
    for (int t = 0; t < 4; ++t) {
        int col = col0 + t * 16 + l16;
        float bb = bias ? bias[col] : 0.f;
#pragma unroll
        for (int r = 0; r < 4; ++r) {
            int row = row0 + quad * 4 + r;
            if (row < M) {
                float o = acc[t][r] + bb;
                if (act == 1) o = fmaxf(o, 0.f);
                else if (act == 2) o = o >= 0.f ? o : a * o;
                C[(size_t)row * N + col] = o;
            }
        }
    }
}

extern "C" void kernel_launch(void* const* d_in, const int* in_sizes, int n_in,
                              void* d_out, int out_size, void* d_ws, size_t ws_size,
                              hipStream_t stream) {
    const float* x     = (const float*)d_in[0];
    const int*   ei    = (const int*)d_in[1];   // harness materializes int64 as int32
    const float* W1    = (const float*)d_in[2];
    const float* b1    = (const float*)d_in[3];
    const float* W2    = (const float*)d_in[4];
    const float* b2    = (const float*)d_in[5];
    const float* a_ptr = (const float*)d_in[6];
    const float* fc1_w = (const float*)d_in[7];
    const float* fc1_b = (const float*)d_in[8];
    const float* fc2_w = (const float*)d_in[9];
    const float* fc2_b = (const float*)d_in[10];

    const int n = in_sizes[0] / 128;
    const int E = in_sizes[1] / 2;
    const int* src = ei;
    const int* dst = ei + E;
    const int nb = (n + 1023) >> 10;            // scan blocks (98 for n=100000)

    float* out_final  = (float*)d_out;                    // [n,128]
    float* proj_final = out_final + (size_t)n * 128;      // [n,128]
    float* out1       = (float*)d_out;                    // [n,256] transient

    // workspace carve-out (~59.6 MB total)
    char* p = (char*)d_ws;
    auto take = [&](size_t bytes) -> char* {
        char* q = p;
        p += (bytes + 1023) & ~(size_t)1023;
        return q;
    };
    int*   deg     = (int*)take((size_t)n * 4);
    int*   offsets = (int*)take(((size_t)n + 1) * 4);
    int*   cursor  = (int*)take((size_t)n * 4);
    float* dinv    = (float*)take((size_t)n * 4);
    int*   bsum    = (int*)take((size_t)1024 * 4);
    int*   bbase   = (int*)take((size_t)1024 * 4);
    int*   csr     = (int*)take((size_t)E * 4);
    short* W1t_hi  = (short*)take((size_t)256 * 128 * 2);
    short* W1t_lo  = (short*)take((size_t)256 * 128 * 2);
    short* W2t_hi  = (short*)take((size_t)128 * 256 * 2);
    short* W2t_lo  = (short*)take((size_t)128 * 256 * 2);
    short* f1t_hi  = (short*)take((size_t)128 * 128 * 2);
    short* f1t_lo  = (short*)take((size_t)128 * 128 * 2);
    short* f2t_hi  = (short*)take((size_t)128 * 128 * 2);
    short* f2t_lo  = (short*)take((size_t)128 * 128 * 2);
    float* bufA    = (float*)take((size_t)n * 128 * 4);   // [n,128] f32 scratch

    (void)hipMemsetAsync(deg, 0, (size_t)n * 4, stream);
    (void)hipMemsetAsync(cursor, 0, (size_t)n * 4, stream);

    // ---- weight pre-transpose/split (tiny) ----
    wconv_kernel<<<(128 * 256 + 255) / 256, 256, 0, stream>>>(W1, W1t_hi, W1t_lo, 128, 256);
    wconv_kernel<<<(256 * 128 + 255) / 256, 256, 0, stream>>>(W2, W2t_hi, W2t_lo, 256, 128);
    wconv_kernel<<<(128 * 128 + 255) / 256, 256, 0, stream>>>(fc1_w, f1t_hi, f1t_lo, 128, 128);
    wconv_kernel<<<(128 * 128 + 255) / 256, 256, 0, stream>>>(fc2_w, f2t_hi, f2t_lo, 128, 128);

    // ---- CSR build (shared by both conv layers) ----
    deg_kernel<<<(E + 255) / 256, 256, 0, stream>>>(dst, deg, E);
    part_kernel<<<nb, 256, 0, stream>>>(deg, bsum, dinv, n);
    topscan_kernel<<<1, 1024, 0, stream>>>(bsum, bbase, nb);
    offs_kernel<<<nb, 256, 0, stream>>>(deg, bbase, offsets, n);
    fill_kernel<<<(E + 255) / 256, 256, 0, stream>>>(src, dst, offsets, cursor, csr, E);

    const int mblk = (n + 63) / 64;

    // ---- layer 1: aggregate first (dim 128): aggx = A_hat x -> bufA
    agg128_kernel<<<(n + 3) / 4, 256, 0, stream>>>(x, csr, offsets, dinv,
                                                   nullptr, nullptr, bufA, n);
    // out1 = prelu(aggx @ W1 + b1) -> d_out as [n,256]
    gemm_kernel<<<dim3(mblk, 4), 256, 0, stream>>>(bufA, W1t_hi, W1t_lo, out1,
                                                   n, 128, 256, b1, 2, a_ptr);

    // ---- layer 2: g2 = out1 @ W2 -> bufA [n,128]
    gemm_kernel<<<dim3(mblk, 2), 256, 0, stream>>>(out1, W2t_hi, W2t_lo, bufA,
                                                   n, 256, 128, nullptr, 0, nullptr);
    // out = prelu(A_hat agg of g2 + b2) -> d_out[0 : n*128]
    agg128_kernel<<<(n + 3) / 4, 256, 0, stream>>>(bufA, csr, offsets, dinv,
                                                   b2, a_ptr, out_final, n);

    // ---- MLP head ----
    gemm_kernel<<<dim3(mblk, 2), 256, 0, stream>>>(out_final, f1t_hi, f1t_lo, bufA,
                                                   n, 128, 128, fc1_b, 1, nullptr);
    gemm_kernel<<<dim3(mblk, 2), 256, 0, stream>>>(bufA, f2t_hi, f2t_lo, proj_final,
                                                   n, 128, 128, fc2_b, 0, nullptr);
}

// Round 2
// 816.245 us; speedup vs baseline: 1.3038x; 1.1906x over previous
//
#include <hip/hip_runtime.h>

// GCN: out = prelu(GCNConv2(prelu(GCNConv1(x)))), proj = MLP(out)
// R5: agg128 edge loop unrolled 8-wide (latency -> 8 gathers in flight).
// R6: GEMM rewrite: B fragments register-resident (preloaded once per block,
//     32x bf16x8 = 128 VGPR), operand-swapped MFMA so C layout is
//     row-per-l16 / 4 consecutive cols per reg -> coalesced float4 stores
//     (full 128B lines, no write-allocate). 4 M-tiles per block amortize
//     the B preload. K=256 (W2) runs as two k=128 accumulate launches.

typedef __attribute__((ext_vector_type(4))) float  f32x4;
typedef __attribute__((ext_vector_type(8))) __bf16 bf16x8;
typedef __attribute__((ext_vector_type(8))) short  short8;

__device__ __forceinline__ bf16x8 as_bf(short8 s) {
    union { short8 s; bf16x8 b; } u; u.s = s; return u.b;
}

// truncation split: x = hi + lo + eps, |eps| <= 2^-16 |x|
__device__ __forceinline__ short2 split1(float x) {
    unsigned u = __float_as_uint(x);
    short hi = (short)(u >> 16);
    float hif = __uint_as_float(u & 0xFFFF0000u);
    short lo = (short)(__float_as_uint(x - hif) >> 16);
    return make_short2(hi, lo);
}

// ---------------- degree count ----------------
__global__ void deg_kernel(const int* __restrict__ dst, int* __restrict__ deg, int E) {
    int e = blockIdx.x * blockDim.x + threadIdx.x;
    if (e < E) atomicAdd(&deg[dst[e]], 1);
}

// ---------------- scan phase 1: per-block (1024 elems) sum + dinv ----------------
__global__ __launch_bounds__(256)
void part_kernel(const int* __restrict__ deg, int* __restrict__ bsum,
                 float* __restrict__ dinv, int n) {
    int tid = threadIdx.x;
    int base = blockIdx.x * 1024 + tid * 4;
    int d[4] = {0, 0, 0, 0};
    if (base + 3 < n) {
        int4 v = *(const int4*)(deg + base);
        d[0] = v.x; d[1] = v.y; d[2] = v.z; d[3] = v.w;
    } else {
        for (int j = 0; j < 4; ++j) if (base + j < n) d[j] = deg[base + j];
    }
    for (int j = 0; j < 4; ++j)
        if (base + j < n) dinv[base + j] = rsqrtf((float)(d[j] + 1));
    int s = d[0] + d[1] + d[2] + d[3];
    for (int off = 32; off > 0; off >>= 1) s += __shfl_down(s, off);
    __shared__ int wsum[4];
    if ((tid & 63) == 0) wsum[tid >> 6] = s;
    __syncthreads();
    if (tid == 0) bsum[blockIdx.x] = wsum[0] + wsum[1] + wsum[2] + wsum[3];
}

// ---------------- scan phase 2: single block over block sums ----------------
__global__ __launch_bounds__(1024)
void topscan_kernel(const int* __restrict__ bsum, int* __restrict__ bbase, int nb) {
    __shared__ int sh[1024];
    int tid = threadIdx.x;
    int own = (tid < nb) ? bsum[tid] : 0;
    sh[tid] = own;
    __syncthreads();
    for (int off = 1; off < 1024; off <<= 1) {
        int t = (tid >= off) ? sh[tid - off] : 0;
        __syncthreads();
        sh[tid] += t;
        __syncthreads();
    }
    if (tid < nb) bbase[tid] = sh[tid] - own;   // exclusive
}

// ---------------- scan phase 3: per-block local scan + base -> offsets ----------------
__global__ __launch_bounds__(256)
void offs_kernel(const int* __restrict__ deg, const int* __restrict__ bbase,
                 int* __restrict__ offsets, int n) {
    int tid = threadIdx.x;
    int base = blockIdx.x * 1024 + tid * 4;
    int d[4] = {0, 0, 0, 0};
    if (base + 3 < n) {
        int4 v = *(const int4*)(deg + base);
        d[0] = v.x; d[1] = v.y; d[2] = v.z; d[3] = v.w;
    } else {
        for (int j = 0; j < 4; ++j) if (base + j < n) d[j] = deg[base + j];
    }
    int s = d[0] + d[1] + d[2] + d[3];
    __shared__ int sh[256];
    sh[tid] = s;
    __syncthreads();
    for (int off = 1; off < 256; off <<= 1) {
        int t = (tid >= off) ? sh[tid - off] : 0;
        __syncthreads();
        sh[tid] += t;
        __syncthreads();
    }
    int run = bbase[blockIdx.x] + sh[tid] - s;   // exclusive prefix for this thread
    for (int j = 0; j < 4; ++j) {
        int idx = base + j;
        if (idx <= n) offsets[idx] = run;        // also writes offsets[n]
        if (idx < n) run += d[j];
    }
}

// ---------------- CSR fill ----------------
__global__ void fill_kernel(const int* __restrict__ src, const int* __restrict__ dst,
                            const int* __restrict__ offsets, int* __restrict__ cursor,
                            int* __restrict__ csr, int E) {
    int e = blockIdx.x * blockDim.x + threadIdx.x;
    if (e < E) {
        int d = dst[e];
        int pos = offsets[d] + atomicAdd(&cursor[d], 1);
        csr[pos] = src[e];
    }
}

// ---------------- weight convert: W[K][N] fp32 -> Wt_hi/lo[n][k] bf16 ----------------
__global__ void wconv_kernel(const float* __restrict__ W, short* __restrict__ Wt_hi,
                             short* __restrict__ Wt_lo, int K, int N) {
    int idx = blockIdx.x * blockDim.x + threadIdx.x;
    if (idx >= K * N) return;
    int nn = idx / K, kk = idx - nn * K;
    short2 s = split1(W[(size_t)kk * N + nn]);
    Wt_hi[idx] = s.x;
    Wt_lo[idx] = s.y;
}

// ---------------- aggregation over dim-128 rows, 1 wave per node ----------------
// out[v] = epi( dinv[v] * ( dinv[v]*g[v] + sum_{s->v} dinv[s]*g[s] ) )
// Edge loop is 8-wide: 8 independent 512B row-gathers in flight per wave.
__global__ __launch_bounds__(256)
void agg128_kernel(const float* __restrict__ g, const int* __restrict__ csr,
                   const int* __restrict__ offsets, const float* __restrict__ dinv,
                   const float* __restrict__ bias, const float* __restrict__ a_ptr,
                   float* __restrict__ out, int n) {
    int w = threadIdx.x >> 6;
    int lane = threadIdx.x & 63;
    int v = blockIdx.x * 4 + w;
    if (v >= n) return;
    const char* gb = (const char*)g;          // 32-bit voffset form (51.2 MB buffer)
    unsigned loff = (unsigned)lane * 8u;
    float dv = dinv[v];
    float2 self = *(const float2*)(gb + ((unsigned)v * 512u + loff));
    float accx = dv * self.x;
    float accy = dv * self.y;
    int e = offsets[v], end = offsets[v + 1];
#pragma unroll 1
    for (; e < end; e += 8) {
        int   idx[8];
        float dd[8];
        float2 mm[8];
#pragma unroll
        for (int j = 0; j < 8; ++j) {
            int ee = e + j;
            idx[j] = csr[ee < end ? ee : end - 1];   // clamped dup -> cache hit
        }
#pragma unroll
        for (int j = 0; j < 8; ++j)
            dd[j] = (e + j < end) ? dinv[idx[j]] : 0.f;
#pragma unroll
        for (int j = 0; j < 8; ++j)
            mm[j] = *(const float2*)(gb + ((unsigned)idx[j] * 512u + loff));
#pragma unroll
        for (int j = 0; j < 8; ++j) {
            accx += dd[j] * mm[j].x;
            accy += dd[j] * mm[j].y;
        }
    }
    accx *= dv;
    accy *= dv;
    if (bias) {
        float a = *a_ptr;
        float2 bb = ((const float2*)bias)[lane];
        accx += bb.x;
        accy += bb.y;
        accx = accx >= 0.f ? accx : a * accx;
        accy = accy >= 0.f ? accy : a * accy;
    }
    float2 r; r.x = accx; r.y = accy;
    ((float2*)out)[(size_t)v * 64 + lane] = r;
}

// ---------------- split-bf16 MFMA GEMM, B register-resident ----------------
// C[M][N] = epi( A[M][lda](k_base:k_base+128) @ B + (accum? C : 0) + bias )
// Bt_hi/lo are [N][lda] bf16. Block = 256 thr = 4 waves; block tile 64 rows x
// 64 cols; wave tile 16x64. B frags (4 kt x 4 t x hi/lo = 32 bf16x8) preloaded
// per block. Operand-swapped MFMA: lane l16 = output ROW, regs = 4 consecutive
// cols -> float4 stores. act: 0=none, 1=relu, 2=prelu(a).
__global__ __launch_bounds__(256)
void gemm64_kernel(const float* __restrict__ A, int lda,
                   const short* __restrict__ Bt_hi, const short* __restrict__ Bt_lo,
                   float* __restrict__ C, int M, int N, int k_base,
                   int mtiles, int tpb,
                   const float* __restrict__ bias, int act,
                   const float* __restrict__ a_ptr, int accum) {
    const int tid  = threadIdx.x;
    const int wave = tid >> 6, lane = tid & 63;
    const int quad = lane >> 4, l16 = lane & 15;
    const int col0 = blockIdx.y * 64;

    // B fragments, register-resident for the whole block lifetime.
    bf16x8 bf[4][4][2];
#pragma unroll
    for (int kt = 0; kt < 4; ++kt)
#pragma unroll
        for (int t = 0; t < 4; ++t) {
            size_t off = (size_t)(col0 + t * 16 + l16) * lda + k_base + kt * 32 + quad * 8;
            bf[kt][t][0] = as_bf(*(const short8*)(Bt_hi + off));
            bf[kt][t][1] = as_bf(*(const short8*)(Bt_lo + off));
        }

    const float aw = (act == 2) ? *a_ptr : 0.f;

    const int t0 = blockIdx.x * tpb;
    const int t1 = (t0 + tpb < mtiles) ? t0 + tpb : mtiles;
    for (int tile = t0; tile < t1; ++tile) {
        const int m = tile * 64 + wave * 16 + l16;
        const int mc = m < M ? m : M - 1;
        const float* Ap = A + (size_t)mc * lda + k_base + quad * 8;

        float4 av[8];
#pragma unroll
        for (int kt = 0; kt < 4; ++kt) {
            av[2 * kt]     = *(const float4*)(Ap + kt * 32);
            av[2 * kt + 1] = *(const float4*)(Ap + kt * 32 + 4);
        }

        f32x4 acc[4];
#pragma unroll
        for (int t = 0; t < 4; ++t) acc[t] = (f32x4){0.f, 0.f, 0.f, 0.f};

#pragma unroll
        for (int kt = 0; kt < 4; ++kt) {
            float4 v0 = av[2 * kt], v1 = av[2 * kt + 1];
            short8 ah, al;
            short2 s;
            s = split1(v0.x); ah[0] = s.x; al[0] = s.y;
            s = split1(v0.y); ah[1] = s.x; al[1] = s.y;
            s = split1(v0.z); ah[2] = s.x; al[2] = s.y;
            s = split1(v0.w); ah[3] = s.x; al[3] = s.y;
            s = split1(v1.x); ah[4] = s.x; al[4] = s.y;
            s = split1(v1.y); ah[5] = s.x; al[5] = s.y;
            s = split1(v1.z); ah[6] = s.x; al[6] = s.y;
            s = split1(v1.w); ah[7] = s.x; al[7] = s.y;
            bf16x8 a_hi = as_bf(ah), a_lo = as_bf(al);
#pragma unroll
            for (int t = 0; t < 4; ++t) {
                acc[t] = __builtin_amdgcn_mfma_f32_16x16x32_bf16(bf[kt][t][0], a_hi, acc[t], 0, 0, 0);
                acc[t] = __builtin_amdgcn_mfma_f32_16x16x32_bf16(bf[kt][t][1], a_hi, acc[t], 0, 0, 0);
                acc[t] = __builtin_amdgcn_mfma_f32_16x16x32_bf16(bf[kt][t][0], a_lo, acc[t], 0, 0, 0);
            }
        }

        if (m < M) {
            float* Crow = C + (size_t)m * N + col0 + quad * 4;
#pragma unroll
            for (int t = 0; t < 4; ++t) {
                float4 v;
                v.x = acc[t][0]; v.y = acc[t][1]; v.z = acc[t][2]; v.w = acc[t][3];
                if (accum) {
                    float4 o = *(const float4*)(Crow + t * 16);
                    v.x += o.x; v.y += o.y; v.z += o.z; v.w += o.w;
                }
                if (bias) {
                    float4 bb = *(const float4*)(bias + col0 + t * 16 + quad * 4);
                    v.x += bb.x; v.y += bb.y; v.z += bb.z; v.w += bb.w;
                }
                if (act == 1) {
                    v.x = fmaxf(v.x, 0.f); v.y = fmaxf(v.y, 0.f);
                    v.z = fmaxf(v.z, 0.f); v.w = fmaxf(v.w, 0.f);
                } else if (act == 2) {
                    v.x = v.x >= 0.f ? v.x : aw * v.x;
                    v.y = v.y >= 0.f ? v.y : aw * v.y;
                    v.z = v.z >= 0.f ? v.z : aw * v.z;
                    v.w = v.w >= 0.f ? v.w : aw * v.w;
                }
                *(float4*)(Crow + t * 16) = v;
            }
        }
    }
}

extern "C" void kernel_launch(void* const* d_in, const int* in_sizes, int n_in,
                              void* d_out, int out_size, void* d_ws, size_t ws_size,
                              hipStream_t stream) {
    const float* x     = (const float*)d_in[0];
    const int*   ei    = (const int*)d_in[1];   // harness materializes int64 as int32
    const float* W1    = (const float*)d_in[2];
    const float* b1    = (const float*)d_in[3];
    const float* W2    = (const float*)d_in[4];
    const float* b2    = (const float*)d_in[5];
    const float* a_ptr = (const float*)d_in[6];
    const float* fc1_w = (const float*)d_in[7];
    const float* fc1_b = (const float*)d_in[8];
    const float* fc2_w = (const float*)d_in[9];
    const float* fc2_b = (const float*)d_in[10];

    const int n = in_sizes[0] / 128;
    const int E = in_sizes[1] / 2;
    const int* src = ei;
    const int* dst = ei + E;
    const int nb = (n + 1023) >> 10;            // scan blocks (98 for n=100000)

    float* out_final  = (float*)d_out;                    // [n,128]
    float* proj_final = out_final + (size_t)n * 128;      // [n,128]
    float* out1       = (float*)d_out;                    // [n,256] transient

    // workspace carve-out (~59.6 MB total)
    char* p = (char*)d_ws;
    auto take = [&](size_t bytes) -> char* {
        char* q = p;
        p += (bytes + 1023) & ~(size_t)1023;
        return q;
    };
    int*   deg     = (int*)take((size_t)n * 4);
    int*   offsets = (int*)take(((size_t)n + 1) * 4);
    int*   cursor  = (int*)take((size_t)n * 4);
    float* dinv    = (float*)take((size_t)n * 4);
    int*   bsum    = (int*)take((size_t)1024 * 4);
    int*   bbase   = (int*)take((size_t)1024 * 4);
    int*   csr     = (int*)take((size_t)E * 4);
    short* W1t_hi  = (short*)take((size_t)256 * 128 * 2);
    short* W1t_lo  = (short*)take((size_t)256 * 128 * 2);
    short* W2t_hi  = (short*)take((size_t)128 * 256 * 2);
    short* W2t_lo  = (short*)take((size_t)128 * 256 * 2);
    short* f1t_hi  = (short*)take((size_t)128 * 128 * 2);
    short* f1t_lo  = (short*)take((size_t)128 * 128 * 2);
    short* f2t_hi  = (short*)take((size_t)128 * 128 * 2);
    short* f2t_lo  = (short*)take((size_t)128 * 128 * 2);
    float* bufA    = (float*)take((size_t)n * 128 * 4);   // [n,128] f32 scratch

    (void)hipMemsetAsync(deg, 0, (size_t)n * 4, stream);
    (void)hipMemsetAsync(cursor, 0, (size_t)n * 4, stream);

    // ---- weight pre-transpose/split (tiny) ----
    wconv_kernel<<<(128 * 256 + 255) / 256, 256, 0, stream>>>(W1, W1t_hi, W1t_lo, 128, 256);
    wconv_kernel<<<(256 * 128 + 255) / 256, 256, 0, stream>>>(W2, W2t_hi, W2t_lo, 256, 128);
    wconv_kernel<<<(128 * 128 + 255) / 256, 256, 0, stream>>>(fc1_w, f1t_hi, f1t_lo, 128, 128);
    wconv_kernel<<<(128 * 128 + 255) / 256, 256, 0, stream>>>(fc2_w, f2t_hi, f2t_lo, 128, 128);

    // ---- CSR build (shared by both conv layers) ----
    deg_kernel<<<(E + 255) / 256, 256, 0, stream>>>(dst, deg, E);
    part_kernel<<<nb, 256, 0, stream>>>(deg, bsum, dinv, n);
    topscan_kernel<<<1, 1024, 0, stream>>>(bsum, bbase, nb);
    offs_kernel<<<nb, 256, 0, stream>>>(deg, bbase, offsets, n);
    fill_kernel<<<(E + 255) / 256, 256, 0, stream>>>(src, dst, offsets, cursor, csr, E);

    const int mtiles = (n + 63) / 64;
    const int TPB = 4;
    const int gx = (mtiles + TPB - 1) / TPB;

    // ---- layer 1: aggregate first (dim 128): aggx = A_hat x -> bufA
    agg128_kernel<<<(n + 3) / 4, 256, 0, stream>>>(x, csr, offsets, dinv,
                                                   nullptr, nullptr, bufA, n);
    // out1 = prelu(aggx @ W1 + b1) -> d_out as [n,256]
    gemm64_kernel<<<dim3(gx, 4), 256, 0, stream>>>(bufA, 128, W1t_hi, W1t_lo, out1,
                                                   n, 256, 0, mtiles, TPB, b1, 2, a_ptr, 0);

    // ---- layer 2: g2 = out1 @ W2 -> bufA [n,128]  (K=256 as two k=128 halves)
    gemm64_kernel<<<dim3(gx, 2), 256, 0, stream>>>(out1, 256, W2t_hi, W2t_lo, bufA,
                                                   n, 128, 0, mtiles, TPB, nullptr, 0, nullptr, 0);
    gemm64_kernel<<<dim3(gx, 2), 256, 0, stream>>>(out1, 256, W2t_hi, W2t_lo, bufA,
                                                   n, 128, 128, mtiles, TPB, nullptr, 0, nullptr, 1);
    // out = prelu(A_hat agg of g2 + b2) -> d_out[0 : n*128]
    agg128_kernel<<<(n + 3) / 4, 256, 0, stream>>>(bufA, csr, offsets, dinv,
                                                   b2, a_ptr, out_final, n);

    // ---- MLP head ----
    gemm64_kernel<<<dim3(gx, 2), 256, 0, stream>>>(out_final, 128, f1t_hi, f1t_lo, bufA,
                                                   n, 128, 0, mtiles, TPB, fc1_b, 1, nullptr, 0);
    gemm64_kernel<<<dim3(gx, 2), 256, 0, stream>>>(bufA, 128, f2t_hi, f2t_lo, proj_final,
                                                   n, 128, 0, mtiles, TPB, fc2_b, 0, nullptr, 0);
}